// Round 10
// baseline (183.448 us; speedup 1.0000x reference)
//
#include <hip/hip_runtime.h>
#include <hip/hip_bf16.h>
#include <stdint.h>

// ---------------------------------------------------------------------------
// MHA forward, bf16 MFMA path (gfx950).  B=1, S=4096, D=1024, H=16, HD=64.
//   1. preprocess: cast x->bf16 + transpose-cast Wq|Wk|Wv, Wo
//   2. gemm_qkv: Q -> Qb[4096][1024] (pre-scaled 0.125*log2e); K,V written
//      in FRAGMENT-PACKED layouts Kf/Vf (R16). BK=64 with row-XOR LDS
//      swizzle (R17): store slot' = slot ^ (row&7) via inverse-permuted
//      GLOBAL source (same 128B row -> coalescing intact), read with same
//      XOR. Bank math: bank = (slot*4+word)%32, row-independent; swizzled
//      read spreads 64 lanes over all 32 banks (8-clk optimum); unswizzled
//      BK=64 used only 16 banks -> R5's 2x regression. BK=64 halves the
//      barrier pairs (32 MFMA/step, m97 structure).
//      R8+R9 failed with "container failed twice" = INFRA (audit: no
//      barrier divergence, constant loop bounds, all addresses verified,
//      R5 precedent for staging shape). Third submission unchanged; if it
//      fails again, next round reverts to R7 verbatim as canary.
//   3. flash_attn: R7 kernel UNTOUCHED (measured 48.9 us): packed-K/V dense
//      1KB wave-reads, K+V register ping-pong, setprio on MFMA clusters.
//      Ledger: R0 75 | R1 96 | R2 140 | R3 spill 256 | R4 occ31% 133 |
//      R7 packed 49 -> flash time tracks TA segment count, not occupancy.
//   4. gemm_out: out = Ctx @ Wot^T + bo (fp32), 64x128 tiles, BK=64 + same
//      swizzle.
// ---------------------------------------------------------------------------

typedef __bf16 bf16;
typedef __bf16 bf16x4 __attribute__((ext_vector_type(4)));
typedef __bf16 bf16x8 __attribute__((ext_vector_type(8)));
typedef float  f32x4  __attribute__((ext_vector_type(4)));

#define MFMA32(a, b, c) __builtin_amdgcn_mfma_f32_16x16x32_bf16((a), (b), (c), 0, 0, 0)

static constexpr int S_LEN  = 4096;
static constexpr int DMODEL = 1024;
static constexpr int HDIM   = 64;

#define GLOAD_LDS16(g, l)                                                      \
  __builtin_amdgcn_global_load_lds((__attribute__((address_space(1))) void*)(g), \
                                   (__attribute__((address_space(3))) void*)(l), 16, 0, 0)

// ------------- fused preprocess: cast x + 4 weight transposes --------------
__global__ __launch_bounds__(256) void preprocess(const float* __restrict__ x,
                                                  const float* __restrict__ Wq,
                                                  const float* __restrict__ Wk,
                                                  const float* __restrict__ Wv,
                                                  const float* __restrict__ Wo,
                                                  bf16* __restrict__ xb,
                                                  bf16* __restrict__ Wt,
                                                  bf16* __restrict__ Wot) {
  __shared__ float tile[64][65];
  const int t = threadIdx.x, b = blockIdx.x;
  if (b < 1024) {
#pragma unroll
    for (int i = 0; i < 4; i++) {
      int idx = b * 1024 + i * 256 + t;
      float4 v = ((const float4*)x)[idx];
      bf16x4 o;
      o[0] = (bf16)v.x; o[1] = (bf16)v.y; o[2] = (bf16)v.z; o[3] = (bf16)v.w;
      ((bf16x4*)xb)[idx] = o;
    }
    return;
  }
  const int id = b - 1024;
  const int wsel = id >> 8;
  const int t2 = id & 255;
  const int kb = (t2 & 15) * 64, nb = (t2 >> 4) * 64;
  const float* src = (wsel == 0) ? Wq : (wsel == 1) ? Wk : (wsel == 2) ? Wv : Wo;
  bf16* dst = (wsel < 3) ? (Wt + (size_t)wsel * 1024 * 1024) : Wot;
#pragma unroll
  for (int i = 0; i < 16; i++) {
    int idx = t + i * 256;
    int r = idx >> 6, c = idx & 63;
    tile[r][c] = src[(size_t)(kb + r) * 1024 + nb + c];
  }
  __syncthreads();
#pragma unroll
  for (int i = 0; i < 16; i++) {
    int idx = t + i * 256;
    int cc = idx >> 6, rr = idx & 63;
    dst[(size_t)(nb + cc) * 1024 + kb + rr] = (bf16)tile[rr][cc];
  }
}

// ------------------- gemm_qkv: 128x128 tile, K=1024, BK=64 -----------------
// LDS rows are 128B (64 bf16). Swizzle: LDS[row][slot^(row&7)] holds
// global[row][slot] (slot = 16B unit). Write side: linear global_load_lds
// dest; lane l sources col-slot (l&7)^((l>>3)&7). Read side: slot' =
// (kk*4+quad) ^ (l15&7); fragment row&7 == l15&7 for all wm/r offsets
// (multiples of 8/16) -> round-trip identity, bit-identical data.
// Outputs:
//   n0 <  1024 : Qb[row][col] = acc * 0.18033688 (0.125*log2e), stride 1024
//   n0 <  2048 : Kf packed (R16 layout)
//   else       : Vf packed (R16 layout)
__global__ __launch_bounds__(256) void gemm_qkv(const bf16* __restrict__ A,
                                                const bf16* __restrict__ Bt,
                                                bf16* __restrict__ Qb,
                                                bf16* __restrict__ Kf,
                                                bf16* __restrict__ Vf) {
  __shared__ bf16 lsA[128 * 64];
  __shared__ bf16 lsB[128 * 64];
  const int tid = threadIdx.x, w = tid >> 6, lane = tid & 63;
  const int l15 = lane & 15, quad = lane >> 4;
  const int m0 = blockIdx.x * 128, n0 = blockIdx.y * 128;
  const int wm = (w >> 1) * 64, wn = (w & 1) * 64;
  const int rowS = lane >> 3;                         // 0..7 row within chunk
  const int colk = ((lane & 7) ^ (rowS & 7)) * 8;     // inverse-swizzled source
  const int rx = l15 & 7;                             // read-side XOR

  f32x4 acc[4][4] = {};

  for (int k0 = 0; k0 < 1024; k0 += 64) {
    __syncthreads();
#pragma unroll
    for (int i = 0; i < 4; i++) {
      int s = w * 4 + i;                              // 16 chunks of 8 rows
      const bf16* ga = A + (size_t)(m0 + s * 8 + rowS) * 1024 + k0 + colk;
      GLOAD_LDS16(ga, lsA + s * 512);
      const bf16* gb = Bt + (size_t)(n0 + s * 8 + rowS) * 1024 + k0 + colk;
      GLOAD_LDS16(gb, lsB + s * 512);
    }
    __syncthreads();

    bf16x8 af[4][2], bfr[4][2];
#pragma unroll
    for (int r = 0; r < 4; r++)
#pragma unroll
      for (int kk = 0; kk < 2; kk++)
        af[r][kk] = *(const bf16x8*)(lsA + (wm + r * 16 + l15) * 64 +
                                     ((kk * 4 + quad) ^ rx) * 8);
#pragma unroll
    for (int c = 0; c < 4; c++)
#pragma unroll
      for (int kk = 0; kk < 2; kk++)
        bfr[c][kk] = *(const bf16x8*)(lsB + (wn + c * 16 + l15) * 64 +
                                      ((kk * 4 + quad) ^ rx) * 8);
#pragma unroll
    for (int kk = 0; kk < 2; kk++)
#pragma unroll
      for (int r = 0; r < 4; r++)
#pragma unroll
        for (int c = 0; c < 4; c++)
          acc[r][c] = MFMA32(af[r][kk], bfr[c][kk], acc[r][c]);
  }

  if (n0 < 1024) {
    // ---- Q ----
#pragma unroll
    for (int r = 0; r < 4; r++) {
#pragma unroll
      for (int c = 0; c < 4; c++) {
        int col = n0 + wn + c * 16 + l15;
#pragma unroll
        for (int e = 0; e < 4; e++) {
          int row = m0 + wm + r * 16 + quad * 4 + e;
          Qb[(size_t)row * 1024 + col] = (bf16)(acc[r][c][e] * 0.18033688f);
        }
      }
    }
  } else if (n0 < 2048) {
    // ---- K packed ----
    const int h  = (n0 - 1024 + wn) >> 6;
    const int g0 = (m0 + wm) >> 5;
    bf16* base = Kf + (size_t)(h * 128 + g0) * 2048 +
                 (quad & 1) * 1024 + (l15 >> 3) * 128 + (quad >> 1) * 32 + (l15 & 7);
#pragma unroll
    for (int r = 0; r < 4; r++) {
#pragma unroll
      for (int c = 0; c < 4; c++) {
#pragma unroll
        for (int e = 0; e < 4; e++) {
          base[(r >> 1) * 2048 + (r & 1) * 64 + (c >> 1) * 512 + (c & 1) * 256 + e * 8] =
              (bf16)acc[r][c][e];
        }
      }
    }
  } else {
    // ---- V packed ----
    const int h  = (n0 - 2048 + wn) >> 6;
    const int g0 = (m0 + wm) >> 5;
    bf16* base = Vf + (size_t)(h * 128 + g0) * 2048 +
                 (quad >> 1) * 128 + l15 * 8 + (quad & 1) * 4;
#pragma unroll
    for (int r = 0; r < 4; r++) {
#pragma unroll
      for (int c = 0; c < 4; c++) {
        bf16x4 pk;
#pragma unroll
        for (int e = 0; e < 4; e++) pk[e] = (bf16)acc[r][c][e];
        *(bf16x4*)(base + (r >> 1) * 2048 + (r & 1) * 256 + c * 512) = pk;
      }
    }
  }
}

// ----------------------------- flash attention -----------------------------
// R7 kernel, measured 48.9 us — UNTOUCHED. 1024 blocks, one 64-q tile each,
// 4 key-split waves, K+V register ping-pong, permuted S^T packing, chunked
// reduction. K/V loads from fragment-packed Kf/Vf: dense 1KB wave-reads.
__global__ __launch_bounds__(256, 2) void flash_attn(const bf16* __restrict__ Qb,
                                                     const bf16* __restrict__ Kf,
                                                     const bf16* __restrict__ Vf,
                                                     bf16* __restrict__ Ctx) {
  __shared__ float Obuf[4][16][68];   // 17.4 KB: per-wave partial O, one qg chunk
  __shared__ float Lbuf[4][4][64];    // 4 KB
  const int tid = threadIdx.x, w = tid >> 6, lane = tid & 63;
  const int l15 = lane & 15, quad = lane >> 4;
  const int i = blockIdx.x;
  const int head = (i & 7) + 8 * ((i >> 3) & 1);
  const int qt_raw = i >> 4;
  const int qb = (qt_raw < 32) ? qt_raw : (95 - qt_raw);
  const int hq = head * HDIM;

  const int T = (qb >> 1) + 1;              // 128-key tiles

  // Packed per-wave base pointers: group g = j*4 + w.
  const bf16* Kw = Kf + (size_t)(head * 128 + w) * 2048 + lane * 8;
  const bf16* Vw = Vf + (size_t)(head * 128 + w) * 2048 + lane * 8;

  // Q frags (B-operand): q = qb*64 + qg*16 + l15, d = kk*32 + quad*8 + j
  bf16x8 qf[4][2];
#pragma unroll
  for (int qg = 0; qg < 4; qg++)
#pragma unroll
    for (int kk = 0; kk < 2; kk++)
      qf[qg][kk] = *(const bf16x8*)(Qb + (size_t)(qb * 64 + qg * 16 + l15) * 1024 +
                                    hq + kk * 32 + quad * 8);

  f32x4 oacc[4][4] = {};
  float lsum[4] = {0.f, 0.f, 0.f, 0.f};

  auto load_k = [&](int j, bf16x8 (&kf)[2][2]) {
#pragma unroll
    for (int c = 0; c < 2; c++)
#pragma unroll
      for (int kk = 0; kk < 2; kk++)
        kf[c][kk] = *(const bf16x8*)(Kw + j * 8192 + c * 1024 + kk * 512);
  };
  auto load_v = [&](int j, bf16x8 (&vf)[4]) {
#pragma unroll
    for (int dg = 0; dg < 4; dg++)
      vf[dg] = *(const bf16x8*)(Vw + j * 8192 + dg * 512);
  };
  auto compute = [&](int j, bf16x8 (&kf)[2][2], bf16x8 (&vf)[4]) {
    // S^T = K Q^T : C row = key-slot quad*4+e (matrix c), col = q = l15
    f32x4 sacc[2][4] = {};
    __builtin_amdgcn_s_setprio(1);
#pragma unroll
    for (int kk = 0; kk < 2; kk++)
#pragma unroll
      for (int c = 0; c < 2; c++)
#pragma unroll
        for (int qg = 0; qg < 4; qg++)
          sacc[c][qg] = MFMA32(kf[c][kk], qf[qg][kk], sacc[c][qg]);
    __builtin_amdgcn_s_setprio(0);

    bf16x8 pfr[4];
    if (j == T - 1) {
      const int kb0 = j * 128 + w * 32 + quad * 8;   // + 4c + e = actual key
#pragma unroll
      for (int qg = 0; qg < 4; qg++) {
        const int qrow = qb * 64 + qg * 16 + l15;
        bf16x8 pb;
#pragma unroll
        for (int c = 0; c < 2; c++)
#pragma unroll
          for (int e = 0; e < 4; e++) {
            float s = sacc[c][qg][e];
            if (kb0 + 4 * c + e > qrow) s = -1e30f;
            float pv = __builtin_amdgcn_exp2f(s);
            lsum[qg] += pv;
            pb[c * 4 + e] = (bf16)pv;
          }
        pfr[qg] = pb;
      }
    } else {
#pragma unroll
      for (int qg = 0; qg < 4; qg++) {
        bf16x8 pb;
#pragma unroll
        for (int c = 0; c < 2; c++)
#pragma unroll
          for (int e = 0; e < 4; e++) {
            float pv = __builtin_amdgcn_exp2f(sacc[c][qg][e]);
            lsum[qg] += pv;
            pb[c * 4 + e] = (bf16)pv;
          }
        pfr[qg] = pb;
      }
    }

    // O += P V  (K=32, P direct from registers)
    __builtin_amdgcn_s_setprio(1);
#pragma unroll
    for (int qg = 0; qg < 4; qg++)
#pragma unroll
      for (int dg = 0; dg < 4; dg++)
        oacc[qg][dg] = MFMA32(pfr[qg], vf[dg], oacc[qg][dg]);
    __builtin_amdgcn_s_setprio(0);
  };

  bf16x8 kfA[2][2], vfA[4], kfB[2][2], vfB[4];
  load_k(0, kfA); load_v(0, vfA);
  for (int j = 0; j < T; j += 2) {
    if (j + 1 < T) { load_k(j + 1, kfB); load_v(j + 1, vfB); }
    compute(j, kfA, vfA);
    if (j + 2 < T) { load_k(j + 2, kfA); load_v(j + 2, vfA); }
    if (j + 1 < T) compute(j + 1, kfB, vfB);
  }

  // ---- chunked cross-wave reduction: one qg (16 q-rows) at a time ----
#pragma unroll
  for (int qg = 0; qg < 4; qg++)
    Lbuf[w][quad][qg * 16 + l15] = lsum[qg];

  const int row = tid >> 4;               // 0..15 (local q within chunk)
  const int col = (tid & 15) * 4;         // 0..60 (d within head)
  for (int qg = 0; qg < 4; qg++) {
#pragma unroll
    for (int dg = 0; dg < 4; dg++)
#pragma unroll
      for (int e = 0; e < 4; e++)
        Obuf[w][quad * 4 + e][dg * 16 + l15] = oacc[qg][dg][e];
    __syncthreads();                      // writes visible
    f32x4 os = {};
#pragma unroll
    for (int ww = 0; ww < 4; ww++)
      os += *(const f32x4*)&Obuf[ww][row][col];
    float lr = 0.f;
#pragma unroll
    for (int ww = 0; ww < 4; ww++)
#pragma unroll
      for (int qq = 0; qq < 4; qq++)
        lr += Lbuf[ww][qq][qg * 16 + row];
    const float linv = 1.f / lr;
    bf16x4 ob;
#pragma unroll
    for (int e2 = 0; e2 < 4; e2++) ob[e2] = (bf16)(os[e2] * linv);
    *(bf16x4*)(Ctx + (size_t)(qb * 64 + qg * 16 + row) * DMODEL + hq + col) = ob;
    __syncthreads();                      // reads done before next chunk
  }
}

// ---------------- gemm_out: 64x128 tile, K=1024, BK=64, swizzled -----------
__global__ __launch_bounds__(256) void gemm_out(const bf16* __restrict__ A,
                                                const bf16* __restrict__ Bt,
                                                float* __restrict__ C,
                                                const float* __restrict__ bias) {
  __shared__ bf16 lsA[64 * 64];
  __shared__ bf16 lsB[128 * 64];
  const int tid = threadIdx.x, w = tid >> 6, lane = tid & 63;
  const int l15 = lane & 15, quad = lane >> 4;
  const int m0 = blockIdx.x * 64, n0 = blockIdx.y * 128;
  const int wm = (w >> 1) * 32, wn = (w & 1) * 64;
  const int rowS = lane >> 3;                         // 0..7
  const int colk = ((lane & 7) ^ (rowS & 7)) * 8;     // inverse-swizzled source
  const int rx = l15 & 7;                             // read-side XOR

  f32x4 acc[2][4] = {};

  for (int k0 = 0; k0 < 1024; k0 += 64) {
    __syncthreads();
#pragma unroll
    for (int i = 0; i < 6; i++) {
      int s = w * 6 + i;                // 0..23: A chunks 0..7, B chunks 8..23
      if (s < 8) {
        const bf16* ga = A + (size_t)(m0 + s * 8 + rowS) * 1024 + k0 + colk;
        GLOAD_LDS16(ga, lsA + s * 512);
      } else {
        int t = s - 8;
        const bf16* gb = Bt + (size_t)(n0 + t * 8 + rowS) * 1024 + k0 + colk;
        GLOAD_LDS16(gb, lsB + t * 512);
      }
    }
    __syncthreads();

    bf16x8 af[2][2], bfr[4][2];
#pragma unroll
    for (int r = 0; r < 2; r++)
#pragma unroll
      for (int kk = 0; kk < 2; kk++)
        af[r][kk] = *(const bf16x8*)(lsA + (wm + r * 16 + l15) * 64 +
                                     ((kk * 4 + quad) ^ rx) * 8);
#pragma unroll
    for (int c = 0; c < 4; c++)
#pragma unroll
      for (int kk = 0; kk < 2; kk++)
        bfr[c][kk] = *(const bf16x8*)(lsB + (wn + c * 16 + l15) * 64 +
                                      ((kk * 4 + quad) ^ rx) * 8);
#pragma unroll
    for (int kk = 0; kk < 2; kk++)
#pragma unroll
      for (int r = 0; r < 2; r++)
#pragma unroll
        for (int c = 0; c < 4; c++)
          acc[r][c] = MFMA32(af[r][kk], bfr[c][kk], acc[r][c]);
  }

#pragma unroll
  for (int r = 0; r < 2; r++) {
#pragma unroll
    for (int c = 0; c < 4; c++) {
      int col = n0 + wn + c * 16 + l15;
#pragma unroll
      for (int e = 0; e < 4; e++) {
        int row = m0 + wm + r * 16 + quad * 4 + e;
        C[(size_t)row * 1024 + col] = acc[r][c][e] + bias[col];
      }
    }
  }
}

// ------------------------------- launcher ----------------------------------
extern "C" void kernel_launch(void* const* d_in, const int* in_sizes, int n_in,
                              void* d_out, int out_size, void* d_ws, size_t ws_size,
                              hipStream_t stream) {
  const float* x  = (const float*)d_in[0];
  const float* Wq = (const float*)d_in[1];
  const float* Wk = (const float*)d_in[2];
  const float* Wv = (const float*)d_in[3];
  const float* Wo = (const float*)d_in[4];
  const float* bo = (const float*)d_in[5];

  char* ws = (char*)d_ws;                    // 48 MB total
  bf16* xb  = (bf16*)(ws);                   // 8 MB  [4096][1024]
  bf16* Wt  = (bf16*)(ws + (8u  << 20));     // 6 MB  [3072][1024]
  bf16* Wot = (bf16*)(ws + (14u << 20));     // 2 MB  [1024][1024]
  bf16* Qb  = (bf16*)(ws + (16u << 20));     // 8 MB  [4096][1024]
  bf16* Kf  = (bf16*)(ws + (24u << 20));     // 8 MB  packed K frags
  bf16* Vf  = (bf16*)(ws + (32u << 20));     // 8 MB  packed V frags
  bf16* Ctx = (bf16*)(ws + (40u << 20));     // 8 MB  [4096][1024]

  preprocess<<<2048, 256, 0, stream>>>(x, Wq, Wk, Wv, Wo, xb, Wt, Wot);
  gemm_qkv<<<dim3(32, 24), 256, 0, stream>>>(xb, Wt, Qb, Kf, Vf);
  flash_attn<<<1024, 256, 0, stream>>>(Qb, Kf, Vf, Ctx);
  gemm_out<<<dim3(64, 8), 256, 0, stream>>>(Ctx, Wot, (float*)d_out, bo);
}